// Round 4
// baseline (83.194 us; speedup 1.0000x reference)
//
#include <hip/hip_runtime.h>

// GaussianHistogram: hist[b,i,j] = sum_n exp(-pi*(u1-i)^2) * exp(-pi*(u2-j)^2) * mask
// u = (x - MIN_V)/DELTA - 0.5 ; COEF == 1.0 exactly. 3x3 taps around round(u):
// dropped taps at distance >= 1.5 bins (weight <= 8.5e-4, per-cell error ~4e-4
// << 8.6e-2 threshold; measured absmax 0.016 is fp32 accumulation noise).
//
// Round-4 structure: block = (32-row tile, point-quarter, batch) -> 256 blocks.
//  - weight-compute redundancy 32x -> 8x (each point seen by 8 tile-blocks)
//  - per-block point count 32768 -> 8192 (divergent ds-atomic issue /4)
//  - 4 partial tiles per (batch,tile) in d_ws (8 MB), merged by a second kernel
//    whose layout makes it a pure coalesced 4-way float4 sum (L2-warm).

#define BINS   256
#define NPTS   32768
#define BATCH  8
#define TROWS  32
#define NTILE  (BINS / TROWS)      // 8
#define NSPLIT 4                   // point-quarters per batch
#define PPB    (NPTS / NSPLIT)     // 8192 points per block
#define QSTRIDE (BATCH * BINS * BINS)  // 524288 floats between q-partials

static constexpr float kInvDelta = 256.0f / 1.5f;
static constexpr float kUAdd     = 0.25f * (256.0f / 1.5f) - 0.5f;
static constexpr float kPi       = 3.14159265358979323846f;
static constexpr float k2Pi      = 2.0f * kPi;

__global__ __launch_bounds__(1024) void gh_scatter(
    const float* __restrict__ x1, const float* __restrict__ x2,
    const float* __restrict__ mask, float* __restrict__ part)
{
    __shared__ float tile[TROWS * BINS];   // 32 KB
    const int tid  = threadIdx.x;
    const int tl   = blockIdx.x;           // row tile 0..7
    const int q    = blockIdx.y;           // point quarter 0..3
    const int b    = blockIdx.z;           // batch 0..7
    const int r0   = tl * TROWS;

    for (int i = tid; i < TROWS * BINS; i += 1024) tile[i] = 0.0f;
    __syncthreads();

    const float4* X1 = (const float4*)(x1   + b * NPTS + q * PPB);
    const float4* X2 = (const float4*)(x2   + b * NPTS + q * PPB);
    const float4* M  = (const float4*)(mask + b * NPTS + q * PPB);

#pragma unroll
    for (int it = 0; it < PPB / 4096; ++it) {   // 2 iterations of 4 points
        const int n4 = it * 1024 + tid;
        const float4 a4 = X1[n4];
        const float4 b4 = X2[n4];
        const float4 m4 = M[n4];
        const float pv1[4] = {a4.x, a4.y, a4.z, a4.w};
        const float pv2[4] = {b4.x, b4.y, b4.z, b4.w};
        const float pm[4]  = {m4.x, m4.y, m4.z, m4.w};

#pragma unroll
        for (int k = 0; k < 4; ++k) {
            const float u1 = fmaf(pv1[k], kInvDelta, kUAdd);
            const float u2 = fmaf(pv2[k], kInvDelta, kUAdd);
            const float fi = rintf(u1);
            const float fj = rintf(u2);
            int i0 = (int)fi, j0 = (int)fj;
            i0 = min(254, max(1, i0));     // memory-safety (no-op for x in [0,1))
            j0 = min(254, max(1, j0));
            const float t1 = u1 - (float)i0;   // [-0.5, 0.5]
            const float t2 = u2 - (float)j0;

            // exponent(a) = -pi*(t-a)^2 = (-pi t^2) + a*(2pi t) - pi*a^2
            const float q1 = -kPi * t1 * t1, r1 = k2Pi * t1;
            const float q2 = -kPi * t2 * t2, r2 = k2Pi * t2;
            const float w1m = __expf(q1 - r1 - kPi);
            const float w10 = __expf(q1);
            const float w1p = __expf(q1 + r1 - kPi);
            const float w2m = __expf(q2 - r2 - kPi) * pm[k];
            const float w20 = __expf(q2)            * pm[k];
            const float w2p = __expf(q2 + r2 - kPi) * pm[k];
            const float w1[3] = {w1m, w10, w1p};
            const float w2[3] = {w2m, w20, w2p};

            const int rbase = i0 - 1 - r0;
            const int cbase = j0 - 1;
#pragma unroll
            for (int a = 0; a < 3; ++a) {
                const int rr = rbase + a;
                if ((unsigned)rr < TROWS) {
                    const float wa  = w1[a];
                    const int   off = rr * BINS + cbase;
                    atomicAdd(&tile[off + 0], wa * w2[0]);   // ds_add_f32
                    atomicAdd(&tile[off + 1], wa * w2[1]);
                    atomicAdd(&tile[off + 2], wa * w2[2]);
                }
            }
        }
    }
    __syncthreads();

    // partial layout: part[q*QSTRIDE + b*65536 + tl*8192 + r*256 + j]
    float4*       o4 = (float4*)(part + (size_t)q * QSTRIDE + b * 65536 + tl * (TROWS * BINS));
    const float4* t4 = (const float4*)tile;
    for (int i = tid; i < TROWS * BINS / 4; i += 1024) o4[i] = t4[i];
}

__global__ __launch_bounds__(256) void gh_merge(
    const float* __restrict__ part, float* __restrict__ out)
{
    const int i = blockIdx.x * blockDim.x + threadIdx.x;   // over QSTRIDE/4 float4s
    const float4* p4 = (const float4*)part;
    float4 s0 = p4[i];
    float4 s1 = p4[i + QSTRIDE / 4];
    float4 s2 = p4[i + 2 * (QSTRIDE / 4)];
    float4 s3 = p4[i + 3 * (QSTRIDE / 4)];
    float4 r;
    r.x = (s0.x + s1.x) + (s2.x + s3.x);
    r.y = (s0.y + s1.y) + (s2.y + s3.y);
    r.z = (s0.z + s1.z) + (s2.z + s3.z);
    r.w = (s0.w + s1.w) + (s2.w + s3.w);
    ((float4*)out)[i] = r;   // full overwrite of poisoned d_out
}

extern "C" void kernel_launch(void* const* d_in, const int* in_sizes, int n_in,
                              void* d_out, int out_size, void* d_ws, size_t ws_size,
                              hipStream_t stream) {
    const float* x1   = (const float*)d_in[0];
    const float* x2   = (const float*)d_in[1];
    const float* mask = (const float*)d_in[2];
    float*       out  = (float*)d_out;
    float*       part = (float*)d_ws;   // needs NSPLIT*QSTRIDE*4 = 8 MB

    gh_scatter<<<dim3(NTILE, NSPLIT, BATCH), 1024, 0, stream>>>(x1, x2, mask, part);
    gh_merge<<<(QSTRIDE / 4) / 256, 256, 0, stream>>>(part, out);
}

// Round 5
// 82.562 us; speedup vs baseline: 1.0076x; 1.0076x over previous
//
#include <hip/hip_runtime.h>

// GaussianHistogram: hist[b,i,j] = sum_n exp(-pi*(u1-i)^2) * exp(-pi*(u2-j)^2) * mask
// u = (x - MIN_V)/DELTA - 0.5 ; COEF == 1.0. 3x3 taps around round(u)
// (dropped-tap weight <= 8.5e-4; measured absmax 0.0156 << 8.6e-2 threshold).
//
// Round-5: ownership gather (block = batch x 8-row tile, plain-store, no ws)
// with wave-ballot COMPACTION. Only ~10/256 of points touch a given 8-row
// tile, so round-3/4's full-body-every-visit wasted ~96% of wave64 issue
// slots (divergent exps + DS atomics at ~2.5/64 active lanes). Phase 1 scans
// x1 only and compacts hitting point indices into an LDS u16 queue; phase 2
// runs the heavy body densely over ~1280 queued points.

#define BINS  256
#define NPTS  32768
#define BATCH 8
#define TROWS 8
#define NTILE (BINS / TROWS)   // 32 tiles -> 256 blocks, 1/CU
#define QMAX  6144             // mean hits ~1280, sigma ~35 -> no overflow

static constexpr float kInvDelta = 256.0f / 1.5f;
static constexpr float kUAdd     = 0.25f * (256.0f / 1.5f) - 0.5f;
static constexpr float kPi       = 3.14159265358979323846f;
static constexpr float k2Pi      = 2.0f * kPi;

__global__ __launch_bounds__(1024) void gh_gather(
    const float* __restrict__ x1, const float* __restrict__ x2,
    const float* __restrict__ mask, float* __restrict__ out)
{
    __shared__ float          tile[TROWS * BINS];  // 8 KB
    __shared__ unsigned short queue[QMAX];         // 12 KB
    __shared__ int            qcnt;

    const int tid  = threadIdx.x;
    const int lane = tid & 63;
    const int r0   = blockIdx.x * TROWS;
    const int b    = blockIdx.y;

    for (int i = tid; i < TROWS * BINS; i += 1024) tile[i] = 0.0f;
    if (tid == 0) qcnt = 0;
    __syncthreads();

    // ---- phase 1: row-gate on x1 only, wave-compact hit indices ----
    const float4* X1 = (const float4*)(x1 + b * NPTS);
#pragma unroll
    for (int it = 0; it < NPTS / 4096; ++it) {        // 8 slots, 4 points each
        const int    n4 = it * 1024 + tid;
        const float4 a4 = X1[n4];
        const float  pv[4] = {a4.x, a4.y, a4.z, a4.w};

        bool h[4];
#pragma unroll
        for (int k = 0; k < 4; ++k) {
            const float u1 = fmaf(pv[k], kInvDelta, kUAdd);
            const int   i0 = (int)rintf(u1);
            h[k] = (unsigned)(i0 - 1 - r0 + 2) < (unsigned)(TROWS + 2);
        }
        unsigned long long bal[4];
        int cnt[4];
#pragma unroll
        for (int k = 0; k < 4; ++k) { bal[k] = __ballot(h[k]); cnt[k] = __popcll(bal[k]); }

        int wb = 0;
        if (lane == 0) wb = atomicAdd(&qcnt, cnt[0] + cnt[1] + cnt[2] + cnt[3]);
        wb = __shfl(wb, 0, 64);

        const unsigned long long below = (lane == 63) ? ~0ull >> 1
                                       : ((1ull << lane) - 1ull);
        int run = wb;
#pragma unroll
        for (int k = 0; k < 4; ++k) {
            if (h[k]) {
                const int idx = run + __popcll(bal[k] & below);
                if (idx < QMAX) queue[idx] = (unsigned short)(n4 * 4 + k);
            }
            run += cnt[k];
        }
    }
    __syncthreads();

    // ---- phase 2: dense heavy body over queued points ----
    const int qn = min(qcnt, QMAX);
    const int pbase = b * NPTS;
    for (int k = tid; k < qn; k += 1024) {
        const int   n  = queue[k];
        const float v1 = x1[pbase + n];
        const float v2 = x2[pbase + n];
        const float m  = mask[pbase + n];

        const float u1 = fmaf(v1, kInvDelta, kUAdd);
        const float u2 = fmaf(v2, kInvDelta, kUAdd);
        const int   i0 = (int)rintf(u1);
        int         j0 = (int)rintf(u2);
        j0 = min(254, max(1, j0));                 // memory-safety (no-op here)
        const float t1 = u1 - (float)i0;
        const float t2 = u2 - (float)j0;

        // exp(-pi*(t-a)^2) = exp((-pi t^2) + a*(2pi t) - pi a^2), a = -1,0,1
        const float e1 = -kPi * t1 * t1, s1 = k2Pi * t1;
        const float e2 = -kPi * t2 * t2, s2 = k2Pi * t2;
        const float w1[3] = {__expf(e1 - s1 - kPi), __expf(e1), __expf(e1 + s1 - kPi)};
        const float w2[3] = {__expf(e2 - s2 - kPi) * m, __expf(e2) * m,
                             __expf(e2 + s2 - kPi) * m};

        const int rbase = i0 - 1 - r0;
        const int cbase = j0 - 1;
#pragma unroll
        for (int a = 0; a < 3; ++a) {
            const int rr = rbase + a;
            if ((unsigned)rr < TROWS) {
                const int off = rr * BINS + cbase;
                atomicAdd(&tile[off + 0], w1[a] * w2[0]);   // ds_add_f32
                atomicAdd(&tile[off + 1], w1[a] * w2[1]);
                atomicAdd(&tile[off + 2], w1[a] * w2[2]);
            }
        }
    }
    __syncthreads();

    // ---- epilogue: plain coalesced store of the owned 8x256 tile ----
    float4*       o4 = (float4*)(out + ((size_t)b * BINS + r0) * BINS);
    const float4* t4 = (const float4*)tile;
    for (int i = tid; i < TROWS * BINS / 4; i += 1024) o4[i] = t4[i];
}

extern "C" void kernel_launch(void* const* d_in, const int* in_sizes, int n_in,
                              void* d_out, int out_size, void* d_ws, size_t ws_size,
                              hipStream_t stream) {
    const float* x1   = (const float*)d_in[0];
    const float* x2   = (const float*)d_in[1];
    const float* mask = (const float*)d_in[2];
    float*       out  = (float*)d_out;

    gh_gather<<<dim3(NTILE, BATCH), 1024, 0, stream>>>(x1, x2, mask, out);
}